// Round 2
// baseline (16912.552 us; speedup 1.0000x reference)
//
#include <hip/hip_runtime.h>
#include <hip/hip_bf16.h>
#include <math.h>

// Problem constants
#define TT 128
#define BB 64
#define HH 512
#define VV 10000
#define TBm (TT*BB)      // 8192
#define H3 (3*HH)        // 1536
#define H2 (2*HH)        // 1024

typedef short bf16x8 __attribute__((ext_vector_type(8)));
typedef float f32x4 __attribute__((ext_vector_type(4)));
typedef __hip_bfloat16 bf16;

// ---------------- small utility kernels ----------------

__global__ void k_init_h(const float* __restrict__ hid, float* __restrict__ h0, float* __restrict__ h1) {
    int g = blockIdx.x * 256 + threadIdx.x;   // 2*BB*HH threads
    if (g < BB*HH) h0[g] = hid[g];
    else           h1[g - BB*HH] = hid[g];
}

__global__ void k_hfinal(const float* __restrict__ h0, const float* __restrict__ h1, float* __restrict__ outp) {
    int g = blockIdx.x * 256 + threadIdx.x;
    outp[g] = (g < BB*HH) ? h0[g] : h1[g - BB*HH];
}

// embedding gather -> f32 X (TB x E), row = t*B+b  (f32: feeds the recurrent chain)
__global__ void k_gather(const int* __restrict__ tok, const float* __restrict__ emb, float* __restrict__ X) {
    size_t g = (size_t)blockIdx.x * 256 + threadIdx.x;
    int row = (int)(g >> 9);
    int e   = (int)(g & 511);
    X[g] = emb[(size_t)tok[row] * HH + e];
}

// generic f32 -> bf16
__global__ void k_cvt(const float* __restrict__ in, bf16* __restrict__ out, int n) {
    int g = blockIdx.x * 256 + threadIdx.x;
    if (g < n) out[g] = __float2bfloat16(in[g]);
}

// A01[k][j] = sum_i fcW0[i][k] * Wx1[i][j]   (f32, feeds recurrent chain)
__global__ void k_a01(const float* __restrict__ fcW0, const float* __restrict__ Wx1, float* __restrict__ A01) {
    int j = blockIdx.x * 256 + threadIdx.x;   // 0..1535
    int k = blockIdx.y;                        // 0..511
    float a = 0.f;
    for (int i = 0; i < HH; i++) a = fmaf(fcW0[(size_t)i * HH + k], Wx1[(size_t)i * H3 + j], a);
    A01[(size_t)k * H3 + j] = a;
}

// b01[j] = sum_i fcb0[i]*Wx1[i][j] + b_rzh1[j]
__global__ void k_b01(const float* __restrict__ fcb0, const float* __restrict__ Wx1,
                      const float* __restrict__ brzh1, float* __restrict__ b01) {
    int j = blockIdx.x * 256 + threadIdx.x;
    float a = brzh1[j];
    for (int i = 0; i < HH; i++) a = fmaf(fcb0[i], Wx1[(size_t)i * H3 + j], a);
    b01[j] = a;
}

// ---------------- f32 GEMM: C[M,N] = A[M,K] @ W[K,N] + bias[N] ----------------
// Vector-ALU (no f32 MFMA on CDNA4). 64x64 tile, BK=16, 256 threads, 4x4/thread.
// Requires M%64==0, N%64==0, K%16==0. LDS rows padded to 68 floats (272B, 16B-aligned).
__global__ __launch_bounds__(256) void gemm_f32(const float* __restrict__ A,
                                                const float* __restrict__ W,
                                                const float* __restrict__ bias,
                                                float* __restrict__ C,
                                                int M, int N, int K) {
    __shared__ float As[16][68];   // As[k][m]
    __shared__ float Ws[16][68];   // Ws[k][n]
    const int tid = threadIdx.x;
    const int tx = tid & 15, ty = tid >> 4;
    const int m0 = blockIdx.y * 64, n0 = blockIdx.x * 64;
    float acc[4][4];
    for (int i = 0; i < 4; i++) for (int j = 0; j < 4; j++) acc[i][j] = 0.f;

    const int ar = tid >> 2, ac4 = (tid & 3) * 4;   // A-stage coords
    const int wk = tid >> 4, wc = (tid & 15) * 4;   // W-stage coords

    for (int kk = 0; kk < K; kk += 16) {
        float4 av = *(const float4*)&A[(size_t)(m0 + ar) * K + kk + ac4];
        As[ac4 + 0][ar] = av.x; As[ac4 + 1][ar] = av.y;
        As[ac4 + 2][ar] = av.z; As[ac4 + 3][ar] = av.w;
        *(float4*)&Ws[wk][wc] = *(const float4*)&W[(size_t)(kk + wk) * N + n0 + wc];
        __syncthreads();
        #pragma unroll
        for (int k = 0; k < 16; k++) {
            float4 a = *(const float4*)&As[k][ty * 4];
            float4 w = *(const float4*)&Ws[k][tx * 4];
            acc[0][0] = fmaf(a.x, w.x, acc[0][0]); acc[0][1] = fmaf(a.x, w.y, acc[0][1]);
            acc[0][2] = fmaf(a.x, w.z, acc[0][2]); acc[0][3] = fmaf(a.x, w.w, acc[0][3]);
            acc[1][0] = fmaf(a.y, w.x, acc[1][0]); acc[1][1] = fmaf(a.y, w.y, acc[1][1]);
            acc[1][2] = fmaf(a.y, w.z, acc[1][2]); acc[1][3] = fmaf(a.y, w.w, acc[1][3]);
            acc[2][0] = fmaf(a.z, w.x, acc[2][0]); acc[2][1] = fmaf(a.z, w.y, acc[2][1]);
            acc[2][2] = fmaf(a.z, w.z, acc[2][2]); acc[2][3] = fmaf(a.z, w.w, acc[2][3]);
            acc[3][0] = fmaf(a.w, w.x, acc[3][0]); acc[3][1] = fmaf(a.w, w.y, acc[3][1]);
            acc[3][2] = fmaf(a.w, w.z, acc[3][2]); acc[3][3] = fmaf(a.w, w.w, acc[3][3]);
        }
        __syncthreads();
    }
    for (int i = 0; i < 4; i++) {
        size_t row = (size_t)(m0 + ty * 4 + i) * N;
        for (int j = 0; j < 4; j++) {
            int col = n0 + tx * 4 + j;
            C[row + col] = acc[i][j] + bias[col];
        }
    }
}

// ---------------- bf16 MFMA GEMM: C[M,N] = A[M,K] @ B[N,K]^T + bias[N] ----------------
// Decode phase only (no feedback into recurrence). 128x128 tile, BK=32, 256 threads,
// mfma_f32_16x16x32_bf16. LDS rows padded to 40 ushorts.
template<bool OUT_BF16>
__global__ __launch_bounds__(256) void gemm_bt(const ushort* __restrict__ A,
                                               const ushort* __restrict__ B,
                                               const float* __restrict__ bias,
                                               void* __restrict__ Cout,
                                               int M, int N, int K) {
    __shared__ ushort As[128 * 40];
    __shared__ ushort Bs[128 * 40];
    const int tid  = threadIdx.x;
    const int m0   = blockIdx.y * 128;
    const int n0   = blockIdx.x * 128;
    const int wave = tid >> 6, lane = tid & 63;
    const int wm   = (wave >> 1) * 64, wn = (wave & 1) * 64;
    const int l16  = lane & 15, quad = lane >> 4;

    f32x4 acc[4][4];
    {
        f32x4 zz = {0.f, 0.f, 0.f, 0.f};
        for (int i = 0; i < 4; i++) for (int j = 0; j < 4; j++) acc[i][j] = zz;
    }

    for (int kk = 0; kk < K; kk += 32) {
        for (int q = tid; q < 512; q += 256) {
            int r = q >> 2, c = (q & 3) * 8;
            *(bf16x8*)&As[r * 40 + c] = *(const bf16x8*)&A[(size_t)(m0 + r) * K + kk + c];
        }
        for (int q = tid; q < 512; q += 256) {
            int r = q >> 2, c = (q & 3) * 8;
            bf16x8 v; for (int i = 0; i < 8; i++) v[i] = 0;
            if (n0 + r < N) v = *(const bf16x8*)&B[(size_t)(n0 + r) * K + kk + c];
            *(bf16x8*)&Bs[r * 40 + c] = v;
        }
        __syncthreads();
        bf16x8 af[4], bg[4];
        for (int mi = 0; mi < 4; mi++) af[mi] = *(const bf16x8*)&As[(wm + mi * 16 + l16) * 40 + quad * 8];
        for (int ni = 0; ni < 4; ni++) bg[ni] = *(const bf16x8*)&Bs[(wn + ni * 16 + l16) * 40 + quad * 8];
        for (int mi = 0; mi < 4; mi++)
            for (int ni = 0; ni < 4; ni++)
                acc[mi][ni] = __builtin_amdgcn_mfma_f32_16x16x32_bf16(af[mi], bg[ni], acc[mi][ni], 0, 0, 0);
        __syncthreads();
    }

    for (int mi = 0; mi < 4; mi++)
        for (int ni = 0; ni < 4; ni++) {
            int col = n0 + wn + ni * 16 + l16;
            if (col < N) {
                float bs = bias[col];
                for (int r = 0; r < 4; r++) {
                    int row = m0 + wm + mi * 16 + quad * 4 + r;
                    float o = acc[mi][ni][r] + bs;
                    if (OUT_BF16) ((bf16*)Cout)[(size_t)row * N + col] = __float2bfloat16(o);
                    else          ((float*)Cout)[(size_t)row * N + col] = o;
                }
            }
        }
}

// ---------------- per-step recurrent kernels (all f32) ----------------
// Stage 1: gh0 = h0@U_h0 -> r0,z0,rh0 ; gh1 = h1@U_h1 (raw)
__global__ void k_s1(const float* __restrict__ h0, const float* __restrict__ h1,
                     const float* __restrict__ Uh0, const float* __restrict__ Uh1,
                     const float* __restrict__ GX0_t,
                     float* __restrict__ rh0, float* __restrict__ z0, float* __restrict__ gh1) {
    __shared__ float hs[HH];
    int g = blockIdx.x * 256 + threadIdx.x;
    if (g < BB * HH) {                    // layer-0 r/z path: 128 blocks
        int b = g >> 9, j = g & (HH - 1);
        const float* hv = h0 + (b << 9);
        for (int k = threadIdx.x; k < HH; k += 256) hs[k] = hv[k];
        __syncthreads();
        float dr = 0.f, dz = 0.f;
        #pragma unroll 8
        for (int k = 0; k < HH; k++) {
            float h = hs[k];
            dr = fmaf(h, Uh0[k * H2 + j], dr);
            dz = fmaf(h, Uh0[k * H2 + HH + j], dz);
        }
        float r = 1.f / (1.f + expf(-(dr + GX0_t[b * H3 + j])));
        float z = 1.f / (1.f + expf(-(dz + GX0_t[b * H3 + HH + j])));
        rh0[g] = r * hs[j];
        z0[g]  = z;
    } else {                              // gh1 raw path: 256 blocks
        int g2 = g - BB * HH;
        int b = g2 >> 10, j = g2 & (H2 - 1);
        const float* hv = h1 + (b << 9);
        for (int k = threadIdx.x; k < HH; k += 256) hs[k] = hv[k];
        __syncthreads();
        float d = 0.f;
        #pragma unroll 8
        for (int k = 0; k < HH; k++) d = fmaf(hs[k], Uh1[k * H2 + j], d);
        gh1[g2] = d;
    }
}

// Stage 2: h0' = (1-z0)h0 + z0*tanh(Whx0 + rh0@U_ht0)
__global__ void k_s2(float* __restrict__ h0, const float* __restrict__ rh0,
                     const float* __restrict__ z0, const float* __restrict__ Uht0,
                     const float* __restrict__ GX0_t) {
    __shared__ float hs[HH];
    int g = blockIdx.x * 256 + threadIdx.x;
    int b = g >> 9, j = g & (HH - 1);
    const float* rv = rh0 + (b << 9);
    for (int k = threadIdx.x; k < HH; k += 256) hs[k] = rv[k];
    __syncthreads();
    float t0 = 0.f;
    #pragma unroll 8
    for (int k = 0; k < HH; k++) t0 = fmaf(hs[k], Uht0[k * HH + j], t0);
    float ht = tanhf(GX0_t[b * H3 + 2 * HH + j] + t0);
    float z = z0[g];
    float h = h0[g];
    h0[g] = (1.f - z) * h + z * ht;
}

// Stage 3: gx1 = h0'@A01 + b01 ; r1,z1,rh1 using gh1 from S1
__global__ void k_s3(const float* __restrict__ h0, const float* __restrict__ h1,
                     const float* __restrict__ A01, const float* __restrict__ b01,
                     const float* __restrict__ gh1,
                     float* __restrict__ rh1, float* __restrict__ z1s, float* __restrict__ gxh1) {
    __shared__ float hs[HH];
    int g = blockIdx.x * 256 + threadIdx.x;
    int b = g >> 9, j = g & (HH - 1);
    const float* hv = h0 + (b << 9);
    for (int k = threadIdx.x; k < HH; k += 256) hs[k] = hv[k];
    __syncthreads();
    float ar = 0.f, az = 0.f, ah = 0.f;
    #pragma unroll 4
    for (int k = 0; k < HH; k++) {
        float h = hs[k];
        const float* Ar = A01 + (size_t)k * H3 + j;
        ar = fmaf(h, Ar[0], ar);
        az = fmaf(h, Ar[HH], az);
        ah = fmaf(h, Ar[2 * HH], ah);
    }
    ar += b01[j]; az += b01[HH + j]; ah += b01[2 * HH + j];
    float r = 1.f / (1.f + expf(-(ar + gh1[b * H2 + j])));
    float z = 1.f / (1.f + expf(-(az + gh1[b * H2 + HH + j])));
    rh1[g]  = r * h1[g];
    z1s[g]  = z;
    gxh1[g] = ah;
}

// Stage 4: h1' = (1-z1)h1 + z1*tanh(gxh1 + rh1@U_ht1); emit bf16 row for decode phase
__global__ void k_s4(float* __restrict__ h1, const float* __restrict__ rh1,
                     const float* __restrict__ z1s, const float* __restrict__ gxh1,
                     const float* __restrict__ Uht1, bf16* __restrict__ H1bf_t) {
    __shared__ float hs[HH];
    int g = blockIdx.x * 256 + threadIdx.x;
    int b = g >> 9, j = g & (HH - 1);
    const float* rv = rh1 + (b << 9);
    for (int k = threadIdx.x; k < HH; k += 256) hs[k] = rv[k];
    __syncthreads();
    float t1 = 0.f;
    #pragma unroll 8
    for (int k = 0; k < HH; k++) t1 = fmaf(hs[k], Uht1[k * HH + j], t1);
    float ht = tanhf(gxh1[g] + t1);
    float z = z1s[g];
    float h = h1[g];
    float hn = (1.f - z) * h + z * ht;
    h1[g] = hn;
    H1bf_t[g] = __float2bfloat16(hn);
}

// ---------------- launcher ----------------
extern "C" void kernel_launch(void* const* d_in, const int* in_sizes, int n_in,
                              void* d_out, int out_size, void* d_ws, size_t ws_size,
                              hipStream_t stream) {
    const int*   tok  = (const int*)d_in[0];
    const float* hid  = (const float*)d_in[1];
    const float* emb  = (const float*)d_in[2];
    const float* W_x  = (const float*)d_in[3];
    const float* U_h  = (const float*)d_in[4];
    const float* U_ht = (const float*)d_in[5];
    const float* brzh = (const float*)d_in[6];
    const float* fcW  = (const float*)d_in[7];
    const float* fcb  = (const float*)d_in[8];
    const float* decW = (const float*)d_in[9];
    const float* decb = (const float*)d_in[10];
    float* out = (float*)d_out;

    char* p = (char*)d_ws;
    auto carve = [&](size_t bytes) { char* r = p; p += (bytes + 255) & ~(size_t)255; return r; };
    float* GX0   = (float*)carve((size_t)TBm * H3 * 4);  // 50 MB (f32: feeds recurrence)
    float* Xf    = (float*)carve((size_t)TBm * HH * 4);  // 16 MB (aliased by Inp2b in decode)
    bf16* fcW1b  = (bf16*)carve((size_t)HH * HH * 2);
    bf16* decWb  = (bf16*)carve((size_t)VV * HH * 2);    // 10 MB
    bf16* H1bf   = (bf16*)carve((size_t)TBm * HH * 2);   // 8 MB
    float* A01   = (float*)carve((size_t)HH * H3 * 4);   // 3 MB
    float* b01   = (float*)carve((size_t)H3 * 4);
    float* h0    = (float*)carve((size_t)BB * HH * 4);
    float* h1    = (float*)carve((size_t)BB * HH * 4);
    float* gh1   = (float*)carve((size_t)BB * H2 * 4);
    float* rh0   = (float*)carve((size_t)BB * HH * 4);
    float* z0    = (float*)carve((size_t)BB * HH * 4);
    float* rh1   = (float*)carve((size_t)BB * HH * 4);
    float* z1s   = (float*)carve((size_t)BB * HH * 4);
    float* gxh1  = (float*)carve((size_t)BB * HH * 4);
    bf16* Inp2b  = (bf16*)Xf;   // reuse Xf region after precompute phase (8 MB < 16 MB)

    const float* Uh0  = U_h;
    const float* Uh1  = U_h + (size_t)HH * H2;
    const float* Uht0 = U_ht;
    const float* Uht1 = U_ht + (size_t)HH * HH;
    const float* Wx1  = W_x + (size_t)HH * H3;

    // --- precompute phase (all parallel) ---
    k_init_h<<<256, 256, 0, stream>>>(hid, h0, h1);
    k_gather<<<(TBm * HH) / 256, 256, 0, stream>>>(tok, emb, Xf);
    k_cvt<<<(HH * HH + 255) / 256, 256, 0, stream>>>(fcW + (size_t)HH * HH, fcW1b, HH * HH);
    k_cvt<<<(VV * HH + 255) / 256, 256, 0, stream>>>(decW, decWb, VV * HH);
    k_a01<<<dim3(6, 512), 256, 0, stream>>>(fcW, Wx1, A01);
    k_b01<<<6, 256, 0, stream>>>(fcb, Wx1, brzh + H3, b01);
    // GX0 = X @ W_x0 + b_rzh0  (f32, W_x0 used in natural (K,N) layout)
    gemm_f32<<<dim3(H3 / 64, TBm / 64), 256, 0, stream>>>(Xf, W_x, brzh, GX0, TBm, H3, HH);

    // --- sequential recurrent phase (all f32) ---
    for (int t = 0; t < TT; t++) {
        const float* GX0_t = GX0 + (size_t)t * BB * H3;
        k_s1<<<384, 256, 0, stream>>>(h0, h1, Uh0, Uh1, GX0_t, rh0, z0, gh1);
        k_s2<<<128, 256, 0, stream>>>(h0, rh0, z0, Uht0, GX0_t);
        k_s3<<<128, 256, 0, stream>>>(h0, h1, A01, b01, gh1, rh1, z1s, gxh1);
        k_s4<<<128, 256, 0, stream>>>(h1, rh1, z1s, gxh1, Uht1, H1bf + (size_t)t * BB * HH);
    }

    // --- decode phase (parallel big GEMMs, bf16 MFMA — no feedback) ---
    gemm_bt<true><<<dim3(HH / 128, TBm / 128), 256, 0, stream>>>(
        (const ushort*)H1bf, (const ushort*)fcW1b, fcb + HH, Inp2b, TBm, HH, HH);
    gemm_bt<false><<<dim3((VV + 127) / 128, TBm / 128), 256, 0, stream>>>(
        (const ushort*)Inp2b, (const ushort*)decWb, decb, out, TBm, VV, HH);

    // h_final tail of d_out
    k_hfinal<<<256, 256, 0, stream>>>(h0, h1, out + (size_t)TBm * VV);
}